// Round 9
// baseline (314.356 us; speedup 1.0000x reference)
//
#include <hip/hip_runtime.h>
#include <math.h>

#define N_NODES 100000
#define N_EDGES 1600000
#define DIM 64
#define CPAD 16      // counters padded to one per 64B cache line

#define NPW 8                    // nodes per wave
#define WPB 4                    // waves per block
#define NPB (NPW * WPB)          // 32 nodes per block
#define NODE_BLOCKS (N_NODES / NPB)   // 3125 exact

#define SCAN_BS   256
#define SCAN_EPB  1024
#define SCAN_NBLK ((N_NODES + SCAN_EPB - 1) / SCAN_EPB)   // 98

// sigmoid(s*w+b) = rcp(1 + exp2(s*(-w*log2e) + (-b*log2e)))
__device__ __forceinline__ float fast_gate(float s, float wl, float bl2) {
    return __builtin_amdgcn_rcpf(1.0f + __builtin_amdgcn_exp2f(fmaf(s, wl, bl2)));
}

// ---------------------------------------------------------------------------
// 1) Histogram of destination rows (4 edges/thread, padded counters).
// ---------------------------------------------------------------------------
__global__ __launch_bounds__(256) void histo_kernel(
    const int* __restrict__ edge, int* __restrict__ cntp)
{
    int t = blockIdx.x * 256 + threadIdx.x;
    if (t >= N_EDGES / 4) return;
    int4 r4 = ((const int4*)edge)[t];
    atomicAdd(&cntp[(size_t)r4.x * CPAD], 1);
    atomicAdd(&cntp[(size_t)r4.y * CPAD], 1);
    atomicAdd(&cntp[(size_t)r4.z * CPAD], 1);
    atomicAdd(&cntp[(size_t)r4.w * CPAD], 1);
}

// ---------------------------------------------------------------------------
// 2a) Per-block reduce of padded cnt.
// ---------------------------------------------------------------------------
__global__ __launch_bounds__(SCAN_BS) void scan_reduce_kernel(
    const int* __restrict__ cntp, int* __restrict__ bsum)
{
    __shared__ int ls[SCAN_BS];
    int base = blockIdx.x * SCAN_EPB;
    int s = 0;
    #pragma unroll
    for (int i = 0; i < 4; ++i) {
        int idx = base + threadIdx.x + i * SCAN_BS;
        s += (idx < N_NODES) ? cntp[(size_t)idx * CPAD] : 0;
    }
    ls[threadIdx.x] = s;
    __syncthreads();
    for (int o = SCAN_BS / 2; o > 0; o >>= 1) {
        if (threadIdx.x < o) ls[threadIdx.x] += ls[threadIdx.x + o];
        __syncthreads();
    }
    if (threadIdx.x == 0) bsum[blockIdx.x] = ls[0];
}

// ---------------------------------------------------------------------------
// 2b) Fused top-scan + per-block rescan. Every block redundantly
//     exclusive-scans the 98 block sums in LDS (saves a kernel launch).
//     Writes off[] (compact) and converts cntp[] in place into the
//     padded scatter cursor (cursor start = off).
// ---------------------------------------------------------------------------
__global__ __launch_bounds__(SCAN_BS) void scan_down_kernel(
    int* __restrict__ cntp, const int* __restrict__ bsum,
    int* __restrict__ off)
{
    __shared__ int ls[SCAN_BS];
    __shared__ int btop[SCAN_NBLK];
    const int tid  = threadIdx.x;
    const int base = blockIdx.x * SCAN_EPB;

    if (tid < SCAN_NBLK) btop[tid] = bsum[tid];
    if (blockIdx.x == 0 && tid == 0) off[N_NODES] = N_EDGES;
    __syncthreads();
    if (tid == 0) {                       // serial exclusive scan of 98 sums
        int run = 0;
        #pragma unroll
        for (int i = 0; i < SCAN_NBLK; ++i) { int t = btop[i]; btop[i] = run; run += t; }
    }

    int v[4]; int tsum = 0;
    #pragma unroll
    for (int i = 0; i < 4; ++i) {
        int idx = base + tid * 4 + i;
        v[i] = (idx < N_NODES) ? cntp[(size_t)idx * CPAD] : 0;
        tsum += v[i];
    }
    ls[tid] = tsum;
    __syncthreads();
    for (int o = 1; o < SCAN_BS; o <<= 1) {
        int t = (tid >= o) ? ls[tid - o] : 0;
        __syncthreads();
        ls[tid] += t;
        __syncthreads();
    }
    int run = btop[blockIdx.x] + ls[tid] - tsum;
    #pragma unroll
    for (int i = 0; i < 4; ++i) {
        int idx = base + tid * 4 + i;
        if (idx < N_NODES) {
            off[idx] = run;
            cntp[(size_t)idx * CPAD] = run;   // in-place padded cursor
        }
        run += v[i];
    }
}

// ---------------------------------------------------------------------------
// 3) Cursor scatter (4 edges/thread): slot = atomicAdd(cursor[row], 1).
//    Padded cursors -> no same-line atomic serialization; 4 independent
//    chains per thread cover the atomic latency.
// ---------------------------------------------------------------------------
__global__ __launch_bounds__(256) void scatter_kernel(
    const int* __restrict__ edge, int* __restrict__ cursorp,
    int* __restrict__ scol)
{
    int t = blockIdx.x * 256 + threadIdx.x;
    if (t >= N_EDGES / 4) return;
    int4 r4 = ((const int4*)edge)[t];
    int4 c4 = ((const int4*)(edge + N_EDGES))[t];
    int p0 = atomicAdd(&cursorp[(size_t)r4.x * CPAD], 1);
    int p1 = atomicAdd(&cursorp[(size_t)r4.y * CPAD], 1);
    int p2 = atomicAdd(&cursorp[(size_t)r4.z * CPAD], 1);
    int p3 = atomicAdd(&cursorp[(size_t)r4.w * CPAD], 1);
    scol[p0] = c4.x;
    scol[p1] = c4.y;
    scol[p2] = c4.z;
    scol[p3] = c4.w;
}

// ---------------------------------------------------------------------------
// 4) Per-node fused gather+gate+mean+Linear+GELU (proven config: ~107us).
//    32 nodes/block, 8 nodes/wave. Per node:
//      Phase A: lane=edge -> {col, |curv diff|} into LDS (once per edge).
//      Phase B: lane (eg,fg) -> float4 x-gather (32-bit saddr) + 4 gates+fmas.
//      Reduce via shfl_xor(16|32); Linear via float4 LDS reads.
// ---------------------------------------------------------------------------
__global__ __launch_bounds__(256) void node_kernel(
    const float* __restrict__ x,    const float* __restrict__ curv,
    const int*   __restrict__ off,  const int* __restrict__ scol,
    const float* __restrict__ Wc,   const float* __restrict__ bc,
    const float* __restrict__ Wl,   const float* __restrict__ bl,
    float* __restrict__ out)
{
    __shared__ float Ws[64][65];
    __shared__ float msl[WPB][64];
    __shared__ int2  ecd[WPB][64];

    const int tid = threadIdx.x;
    #pragma unroll
    for (int i = tid; i < DIM * DIM; i += 256)
        Ws[i >> 6][i & 63] = Wl[i];
    __syncthreads();

    const int sub  = tid >> 6;          // wave in block
    const int lane = tid & 63;
    const int eg   = lane >> 4;         // edge group 0..3
    const int fg   = (lane & 15) << 2;  // feature quad base
    const int d    = lane;              // output feature for Linear

    const float L2E = 1.44269504088896340736f;
    const float4 wc4 = *(const float4*)&Wc[fg];
    const float4 bc4 = *(const float4*)&bc[fg];
    const float wl0 = -wc4.x * L2E, wl1 = -wc4.y * L2E,
                wl2 = -wc4.z * L2E, wl3 = -wc4.w * L2E;
    const float bq0 = -bc4.x * L2E, bq1 = -bc4.y * L2E,
                bq2 = -bc4.z * L2E, bq3 = -bc4.w * L2E;
    const float bld = bl[d];

    const int nbase = blockIdx.x * NPB + sub * NPW;

    for (int i = 0; i < NPW; ++i) {
        const int   node  = nbase + i;
        const int   start = off[node];
        const int   deg   = off[node + 1] - start;
        const float cn    = curv[node];

        float a0 = 0.f, a1 = 0.f, a2 = 0.f, a3 = 0.f;

        for (int kb = 0; kb < deg; kb += 64) {
            const int pn = min(64, deg - kb);
            // Phase A: one lane per edge
            if (lane < pn) {
                int   c  = scol[start + kb + lane];
                float cd = fabsf(cn - curv[c]);
                ecd[sub][lane] = make_int2(c, __float_as_int(cd));
            }
            // Phase B: group eg handles edges k = eg, eg+4, ... < pn
            int k = eg;
            for (; k + 4 < pn; k += 8) {
                int2 p0 = ecd[sub][k];
                int2 p1 = ecd[sub][k + 4];
                float s0 = __int_as_float(p0.y);
                float s1 = __int_as_float(p1.y);
                float4 x0 = *(const float4*)&x[((unsigned)p0.x << 6) + fg];
                float4 x1 = *(const float4*)&x[((unsigned)p1.x << 6) + fg];
                a0 = fmaf(x0.x, fast_gate(s0, wl0, bq0), a0);
                a1 = fmaf(x0.y, fast_gate(s0, wl1, bq1), a1);
                a2 = fmaf(x0.z, fast_gate(s0, wl2, bq2), a2);
                a3 = fmaf(x0.w, fast_gate(s0, wl3, bq3), a3);
                a0 = fmaf(x1.x, fast_gate(s1, wl0, bq0), a0);
                a1 = fmaf(x1.y, fast_gate(s1, wl1, bq1), a1);
                a2 = fmaf(x1.z, fast_gate(s1, wl2, bq2), a2);
                a3 = fmaf(x1.w, fast_gate(s1, wl3, bq3), a3);
            }
            if (k < pn) {
                int2 p0 = ecd[sub][k];
                float s0 = __int_as_float(p0.y);
                float4 x0 = *(const float4*)&x[((unsigned)p0.x << 6) + fg];
                a0 = fmaf(x0.x, fast_gate(s0, wl0, bq0), a0);
                a1 = fmaf(x0.y, fast_gate(s0, wl1, bq1), a1);
                a2 = fmaf(x0.z, fast_gate(s0, wl2, bq2), a2);
                a3 = fmaf(x0.w, fast_gate(s0, wl3, bq3), a3);
            }
        }

        // sum the 4 edge groups
        a0 += __shfl_xor(a0, 16); a0 += __shfl_xor(a0, 32);
        a1 += __shfl_xor(a1, 16); a1 += __shfl_xor(a1, 32);
        a2 += __shfl_xor(a2, 16); a2 += __shfl_xor(a2, 32);
        a3 += __shfl_xor(a3, 16); a3 += __shfl_xor(a3, 32);

        const float inv = __builtin_amdgcn_rcpf(fmaxf((float)deg, 1.0f));
        if (eg == 0)
            *(float4*)&msl[sub][fg] = make_float4(a0 * inv, a1 * inv, a2 * inv, a3 * inv);

        // Linear + GELU (wave-local; compiler inserts lgkmcnt waits)
        float r = bld;
        #pragma unroll
        for (int q = 0; q < DIM; q += 4) {
            float4 mv = *(const float4*)&msl[sub][q];
            float4 wv = *(const float4*)&Ws[d][q];
            r = fmaf(mv.x, wv.x, r);
            r = fmaf(mv.y, wv.y, r);
            r = fmaf(mv.z, wv.z, r);
            r = fmaf(mv.w, wv.w, r);
        }
        out[(size_t)node * DIM + d] = 0.5f * r * (1.0f + erff(r * 0.70710678118654752f));
    }
}

// ---------------------------------------------------------------------------
extern "C" void kernel_launch(void* const* d_in, const int* in_sizes, int n_in,
                              void* d_out, int out_size, void* d_ws, size_t ws_size,
                              hipStream_t stream) {
    const float* x    = (const float*)d_in[0];
    const float* curv = (const float*)d_in[1];
    const float* Wc   = (const float*)d_in[2];
    const float* bc   = (const float*)d_in[3];
    const float* Wl   = (const float*)d_in[4];
    const float* bl   = (const float*)d_in[5];
    const int*   edge = (const int*)d_in[6];

    float* out = (float*)d_out;

    // Workspace layout (~13.2 MB)
    int* cntp = (int*)d_ws;                          // N*16 padded (6.4 MB); becomes cursor
    int* off  = cntp + (size_t)N_NODES * CPAD;       // N + 1
    int* bsum = off + N_NODES + 1;                   // 128
    int* scol = bsum + 128;                          // E (6.4 MB)

    hipMemsetAsync(cntp, 0, (size_t)N_NODES * CPAD * sizeof(int), stream);

    const int qblk = (N_EDGES / 4 + 255) / 256;      // 1563
    histo_kernel<<<qblk, 256, 0, stream>>>(edge, cntp);
    scan_reduce_kernel<<<SCAN_NBLK, SCAN_BS, 0, stream>>>(cntp, bsum);
    scan_down_kernel<<<SCAN_NBLK, SCAN_BS, 0, stream>>>(cntp, bsum, off);
    scatter_kernel<<<qblk, 256, 0, stream>>>(edge, cntp, scol);
    node_kernel<<<NODE_BLOCKS, 256, 0, stream>>>(
        x, curv, off, scol, Wc, bc, Wl, bl, out);
}

// Round 10
// 201.200 us; speedup vs baseline: 1.5624x; 1.5624x over previous
//
#include <hip/hip_runtime.h>
#include <math.h>

#define N_NODES 100000
#define N_EDGES 1600000
#define DIM 64
#define CPAD 16      // counters padded to one per 64B cache line

#define NPW 8                    // nodes per wave
#define WPB 4                    // waves per block
#define NPB (NPW * WPB)          // 32 nodes per block
#define NODE_BLOCKS (N_NODES / NPB)   // 3125 exact

#define SCAN_BS   256
#define SCAN_EPB  1024
#define SCAN_NBLK ((N_NODES + SCAN_EPB - 1) / SCAN_EPB)   // 98

// sigmoid(s*w+b) = rcp(1 + exp2(s*(-w*log2e) + (-b*log2e)))
__device__ __forceinline__ float fast_gate(float s, float wl, float bl2) {
    return __builtin_amdgcn_rcpf(1.0f + __builtin_amdgcn_exp2f(fmaf(s, wl, bl2)));
}

// ---------------------------------------------------------------------------
// 1) Fused histogram + rank (4 edges/thread). Atomic returns the within-node
//    rank; rank[] is stored COALESCED (int4) — the atomic-free scatter pass
//    then has no latency chain. (R9 lesson: fusing rank+scatter serializes
//    atomic->scattered-store and runs 3.5x slower.)
// ---------------------------------------------------------------------------
__global__ __launch_bounds__(256) void rank_kernel(
    const int* __restrict__ edge, int* __restrict__ cntp,
    int* __restrict__ rank)
{
    int t = blockIdx.x * 256 + threadIdx.x;
    if (t >= N_EDGES / 4) return;
    int4 r4 = ((const int4*)edge)[t];
    int4 o;
    o.x = atomicAdd(&cntp[(size_t)r4.x * CPAD], 1);
    o.y = atomicAdd(&cntp[(size_t)r4.y * CPAD], 1);
    o.z = atomicAdd(&cntp[(size_t)r4.z * CPAD], 1);
    o.w = atomicAdd(&cntp[(size_t)r4.w * CPAD], 1);
    ((int4*)rank)[t] = o;
}

// ---------------------------------------------------------------------------
// 2a) Per-block reduce of padded cnt.
// ---------------------------------------------------------------------------
__global__ __launch_bounds__(SCAN_BS) void scan_reduce_kernel(
    const int* __restrict__ cntp, int* __restrict__ bsum)
{
    __shared__ int ls[SCAN_BS];
    int base = blockIdx.x * SCAN_EPB;
    int s = 0;
    #pragma unroll
    for (int i = 0; i < 4; ++i) {
        int idx = base + threadIdx.x + i * SCAN_BS;
        s += (idx < N_NODES) ? cntp[(size_t)idx * CPAD] : 0;
    }
    ls[threadIdx.x] = s;
    __syncthreads();
    for (int o = SCAN_BS / 2; o > 0; o >>= 1) {
        if (threadIdx.x < o) ls[threadIdx.x] += ls[threadIdx.x + o];
        __syncthreads();
    }
    if (threadIdx.x == 0) bsum[blockIdx.x] = ls[0];
}

// ---------------------------------------------------------------------------
// 2b) Fused top-scan + per-block rescan -> off[] (off[N] = E).
//     Every block redundantly scans the 98 block sums in LDS.
// ---------------------------------------------------------------------------
__global__ __launch_bounds__(SCAN_BS) void scan_down_kernel(
    const int* __restrict__ cntp, const int* __restrict__ bsum,
    int* __restrict__ off)
{
    __shared__ int ls[SCAN_BS];
    __shared__ int btop[SCAN_NBLK];
    const int tid  = threadIdx.x;
    const int base = blockIdx.x * SCAN_EPB;

    if (tid < SCAN_NBLK) btop[tid] = bsum[tid];
    if (blockIdx.x == 0 && tid == 0) off[N_NODES] = N_EDGES;
    __syncthreads();
    if (tid == 0) {                       // serial exclusive scan of 98 sums
        int run = 0;
        #pragma unroll
        for (int i = 0; i < SCAN_NBLK; ++i) { int t = btop[i]; btop[i] = run; run += t; }
    }

    int v[4]; int tsum = 0;
    #pragma unroll
    for (int i = 0; i < 4; ++i) {
        int idx = base + tid * 4 + i;
        v[i] = (idx < N_NODES) ? cntp[(size_t)idx * CPAD] : 0;
        tsum += v[i];
    }
    ls[tid] = tsum;
    __syncthreads();
    for (int o = 1; o < SCAN_BS; o <<= 1) {
        int t = (tid >= o) ? ls[tid - o] : 0;
        __syncthreads();
        ls[tid] += t;
        __syncthreads();
    }
    int run = btop[blockIdx.x] + ls[tid] - tsum;
    #pragma unroll
    for (int i = 0; i < 4; ++i) {
        int idx = base + tid * 4 + i;
        if (idx < N_NODES) off[idx] = run;
        run += v[i];
    }
}

// ---------------------------------------------------------------------------
// 3) Atomic-free scatter (4 edges/thread): slot = off[row] + rank[e].
//    All loads coalesced; plain (cached) scattered 4B stores — NT stores
//    measured +23us (R7), cursor-fused measured +100us (R9).
// ---------------------------------------------------------------------------
__global__ __launch_bounds__(256) void scatter_kernel(
    const int* __restrict__ edge, const int* __restrict__ rank,
    const int* __restrict__ off,  int* __restrict__ scol)
{
    int t = blockIdx.x * 256 + threadIdx.x;
    if (t >= N_EDGES / 4) return;
    int4 r4 = ((const int4*)edge)[t];
    int4 c4 = ((const int4*)(edge + N_EDGES))[t];
    int4 k4 = ((const int4*)rank)[t];
    scol[off[r4.x] + k4.x] = c4.x;
    scol[off[r4.y] + k4.y] = c4.y;
    scol[off[r4.z] + k4.z] = c4.z;
    scol[off[r4.w] + k4.w] = c4.w;
}

// ---------------------------------------------------------------------------
// 4) Per-node fused gather+gate+mean+Linear+GELU (proven config: ~107us,
//    FETCH 182MB @ ~2.0TB/s beyond-L2 — the structural wall).
//    32 nodes/block, 8 nodes/wave. Per node:
//      Phase A: lane=edge -> {col, |curv diff|} into LDS (once per edge).
//      Phase B: lane (eg,fg) -> float4 x-gather (32-bit saddr) + 4 gates+fmas.
//      Reduce via shfl_xor(16|32); Linear via float4 LDS reads.
// ---------------------------------------------------------------------------
__global__ __launch_bounds__(256) void node_kernel(
    const float* __restrict__ x,    const float* __restrict__ curv,
    const int*   __restrict__ off,  const int* __restrict__ scol,
    const float* __restrict__ Wc,   const float* __restrict__ bc,
    const float* __restrict__ Wl,   const float* __restrict__ bl,
    float* __restrict__ out)
{
    __shared__ float Ws[64][65];
    __shared__ float msl[WPB][64];
    __shared__ int2  ecd[WPB][64];

    const int tid = threadIdx.x;
    #pragma unroll
    for (int i = tid; i < DIM * DIM; i += 256)
        Ws[i >> 6][i & 63] = Wl[i];
    __syncthreads();

    const int sub  = tid >> 6;          // wave in block
    const int lane = tid & 63;
    const int eg   = lane >> 4;         // edge group 0..3
    const int fg   = (lane & 15) << 2;  // feature quad base
    const int d    = lane;              // output feature for Linear

    const float L2E = 1.44269504088896340736f;
    const float4 wc4 = *(const float4*)&Wc[fg];
    const float4 bc4 = *(const float4*)&bc[fg];
    const float wl0 = -wc4.x * L2E, wl1 = -wc4.y * L2E,
                wl2 = -wc4.z * L2E, wl3 = -wc4.w * L2E;
    const float bq0 = -bc4.x * L2E, bq1 = -bc4.y * L2E,
                bq2 = -bc4.z * L2E, bq3 = -bc4.w * L2E;
    const float bld = bl[d];

    const int nbase = blockIdx.x * NPB + sub * NPW;

    for (int i = 0; i < NPW; ++i) {
        const int   node  = nbase + i;
        const int   start = off[node];
        const int   deg   = off[node + 1] - start;
        const float cn    = curv[node];

        float a0 = 0.f, a1 = 0.f, a2 = 0.f, a3 = 0.f;

        for (int kb = 0; kb < deg; kb += 64) {
            const int pn = min(64, deg - kb);
            // Phase A: one lane per edge
            if (lane < pn) {
                int   c  = scol[start + kb + lane];
                float cd = fabsf(cn - curv[c]);
                ecd[sub][lane] = make_int2(c, __float_as_int(cd));
            }
            // Phase B: group eg handles edges k = eg, eg+4, ... < pn
            int k = eg;
            for (; k + 4 < pn; k += 8) {
                int2 p0 = ecd[sub][k];
                int2 p1 = ecd[sub][k + 4];
                float s0 = __int_as_float(p0.y);
                float s1 = __int_as_float(p1.y);
                float4 x0 = *(const float4*)&x[((unsigned)p0.x << 6) + fg];
                float4 x1 = *(const float4*)&x[((unsigned)p1.x << 6) + fg];
                a0 = fmaf(x0.x, fast_gate(s0, wl0, bq0), a0);
                a1 = fmaf(x0.y, fast_gate(s0, wl1, bq1), a1);
                a2 = fmaf(x0.z, fast_gate(s0, wl2, bq2), a2);
                a3 = fmaf(x0.w, fast_gate(s0, wl3, bq3), a3);
                a0 = fmaf(x1.x, fast_gate(s1, wl0, bq0), a0);
                a1 = fmaf(x1.y, fast_gate(s1, wl1, bq1), a1);
                a2 = fmaf(x1.z, fast_gate(s1, wl2, bq2), a2);
                a3 = fmaf(x1.w, fast_gate(s1, wl3, bq3), a3);
            }
            if (k < pn) {
                int2 p0 = ecd[sub][k];
                float s0 = __int_as_float(p0.y);
                float4 x0 = *(const float4*)&x[((unsigned)p0.x << 6) + fg];
                a0 = fmaf(x0.x, fast_gate(s0, wl0, bq0), a0);
                a1 = fmaf(x0.y, fast_gate(s0, wl1, bq1), a1);
                a2 = fmaf(x0.z, fast_gate(s0, wl2, bq2), a2);
                a3 = fmaf(x0.w, fast_gate(s0, wl3, bq3), a3);
            }
        }

        // sum the 4 edge groups
        a0 += __shfl_xor(a0, 16); a0 += __shfl_xor(a0, 32);
        a1 += __shfl_xor(a1, 16); a1 += __shfl_xor(a1, 32);
        a2 += __shfl_xor(a2, 16); a2 += __shfl_xor(a2, 32);
        a3 += __shfl_xor(a3, 16); a3 += __shfl_xor(a3, 32);

        const float inv = __builtin_amdgcn_rcpf(fmaxf((float)deg, 1.0f));
        if (eg == 0)
            *(float4*)&msl[sub][fg] = make_float4(a0 * inv, a1 * inv, a2 * inv, a3 * inv);

        // Linear + GELU (wave-local; compiler inserts lgkmcnt waits)
        float r = bld;
        #pragma unroll
        for (int q = 0; q < DIM; q += 4) {
            float4 mv = *(const float4*)&msl[sub][q];
            float4 wv = *(const float4*)&Ws[d][q];
            r = fmaf(mv.x, wv.x, r);
            r = fmaf(mv.y, wv.y, r);
            r = fmaf(mv.z, wv.z, r);
            r = fmaf(mv.w, wv.w, r);
        }
        out[(size_t)node * DIM + d] = 0.5f * r * (1.0f + erff(r * 0.70710678118654752f));
    }
}

// ---------------------------------------------------------------------------
extern "C" void kernel_launch(void* const* d_in, const int* in_sizes, int n_in,
                              void* d_out, int out_size, void* d_ws, size_t ws_size,
                              hipStream_t stream) {
    const float* x    = (const float*)d_in[0];
    const float* curv = (const float*)d_in[1];
    const float* Wc   = (const float*)d_in[2];
    const float* bc   = (const float*)d_in[3];
    const float* Wl   = (const float*)d_in[4];
    const float* bl   = (const float*)d_in[5];
    const int*   edge = (const int*)d_in[6];

    float* out = (float*)d_out;

    // Workspace layout (~19.7 MB)
    int* cntp = (int*)d_ws;                          // N*16 padded (6.4 MB)
    int* off  = cntp + (size_t)N_NODES * CPAD;       // N + 1
    int* bsum = off + N_NODES + 1;                   // 128
    int* rank = bsum + 128;                          // E (6.4 MB)
    int* scol = rank + N_EDGES;                      // E (6.4 MB)

    hipMemsetAsync(cntp, 0, (size_t)N_NODES * CPAD * sizeof(int), stream);

    const int qblk = (N_EDGES / 4 + 255) / 256;      // 1563
    rank_kernel<<<qblk, 256, 0, stream>>>(edge, cntp, rank);
    scan_reduce_kernel<<<SCAN_NBLK, SCAN_BS, 0, stream>>>(cntp, bsum);
    scan_down_kernel<<<SCAN_NBLK, SCAN_BS, 0, stream>>>(cntp, bsum, off);
    scatter_kernel<<<qblk, 256, 0, stream>>>(edge, rank, off, scol);
    node_kernel<<<NODE_BLOCKS, 256, 0, stream>>>(
        x, curv, off, scol, Wc, bc, Wl, bl, out);
}

// Round 11
// 150.648 us; speedup vs baseline: 2.0867x; 1.3356x over previous
//
#include <hip/hip_runtime.h>
#include <math.h>

#define N_NODES 100000
#define N_EDGES 1600000
#define DIM 64

#define NBUCK 391        // ceil(100000/256) buckets of 256 rows
#define BCAP  4608       // bucket capacity: mean 4092, +8 sigma
#define TILE  8000       // edges per binA block; 200 * 8000 = E exact

#define NPW 8                    // nodes per wave
#define WPB 4                    // waves per block
#define NPB (NPW * WPB)          // 32 nodes per block
#define NODE_BLOCKS (N_NODES / NPB)   // 3125 exact

// sigmoid(s*w+b) = rcp(1 + exp2(s*(-w*log2e) + (-b*log2e)))
__device__ __forceinline__ float fast_gate(float s, float wl, float bl2) {
    return __builtin_amdgcn_rcpf(1.0f + __builtin_amdgcn_exp2f(fmaf(s, wl, bl2)));
}

// ---------------------------------------------------------------------------
// 1) binA: bucket edges by row>>8 into per-bucket regions of bedge[].
//    Per block: LDS histogram -> one global atomic per (block,bucket)
//    reserves a contiguous run -> packed {lrow:8, col:17} stores land in
//    block-exclusive runs (L2 merges; ~2 line writebacks per run instead
//    of 1 per edge). Replaces rank_kernel (1.6M atomics -> 78k).
// ---------------------------------------------------------------------------
__global__ __launch_bounds__(256) void binA_kernel(
    const int* __restrict__ edge, int* __restrict__ bcnt,
    int* __restrict__ bedge)
{
    __shared__ int hist[NBUCK];
    __shared__ int gbase[NBUCK];
    __shared__ int cur[NBUCK];

    const int t  = threadIdx.x;
    const int e0 = blockIdx.x * TILE;

    for (int i = t; i < NBUCK; i += 256) { hist[i] = 0; cur[i] = 0; }
    __syncthreads();

    // pass 1: bucket histogram (rows only)
    for (int i = t; i < TILE; i += 256)
        atomicAdd(&hist[edge[e0 + i] >> 8], 1);
    __syncthreads();

    // reserve one run per non-empty bucket
    for (int i = t; i < NBUCK; i += 256) {
        int h = hist[i];
        gbase[i] = (h > 0) ? (i * BCAP + atomicAdd(&bcnt[i], h)) : 0;
    }
    __syncthreads();

    // pass 2: place packed edges into reserved runs
    for (int i = t; i < TILE; i += 256) {
        int r = edge[e0 + i];
        int c = edge[N_EDGES + e0 + i];
        int b = r >> 8;
        int lrank = atomicAdd(&cur[b], 1);
        int dst = gbase[b] + lrank;
        if (dst < (b + 1) * BCAP)                 // 8-sigma guard, unreachable
            bedge[dst] = ((r & 255) << 17) | c;
    }
}

// ---------------------------------------------------------------------------
// 2) binC: one block per bucket. Parallel-reduce the bucket's scol base
//    from bcnt[0..b), LDS row-histogram + HS scan -> off[] for its 256
//    rows, then place cols into the bucket's CONTIGUOUS scol window
//    (~16KB, hot in this block's L2 -> minimal writeback).
// ---------------------------------------------------------------------------
__global__ __launch_bounds__(256) void binC_kernel(
    const int* __restrict__ bcnt, const int* __restrict__ bedge,
    int* __restrict__ off, int* __restrict__ scol)
{
    __shared__ int red[256];
    __shared__ int lhist[256];
    __shared__ int lscan[256];
    __shared__ int loff[256];
    __shared__ int lcur[256];

    const int t = threadIdx.x;
    const int b = blockIdx.x;

    // scol base = sum of bcnt[0..b-1]  (strided partial sums + tree reduce)
    int ps = 0;
    for (int i = t; i < b; i += 256) ps += bcnt[i];
    red[t] = ps;
    lhist[t] = 0; lcur[t] = 0;
    __syncthreads();
    for (int o = 128; o > 0; o >>= 1) {
        if (t < o) red[t] += red[t + o];
        __syncthreads();
    }
    const int base = red[0];
    const int nb   = min(bcnt[b], BCAP);
    const int src  = b * BCAP;

    // local row histogram
    for (int j = t; j < nb; j += 256)
        atomicAdd(&lhist[bedge[src + j] >> 17], 1);
    __syncthreads();

    // Hillis-Steele inclusive scan -> exclusive offsets
    int v = lhist[t];
    lscan[t] = v;
    __syncthreads();
    for (int o = 1; o < 256; o <<= 1) {
        int u = (t >= o) ? lscan[t - o] : 0;
        __syncthreads();
        lscan[t] += u;
        __syncthreads();
    }
    loff[t] = lscan[t] - v;
    __syncthreads();

    // off[] for this bucket's rows
    const int row = b * 256 + t;
    if (row < N_NODES) off[row] = base + loff[t];
    if (b == 0 && t == 0) off[N_NODES] = N_EDGES;

    // place cols into the bucket's contiguous scol window
    for (int j = t; j < nb; j += 256) {
        int pv = bedge[src + j];
        int lr = pv >> 17;
        int rk = atomicAdd(&lcur[lr], 1);
        scol[base + loff[lr] + rk] = pv & 0x1FFFF;
    }
}

// ---------------------------------------------------------------------------
// 3) Per-node fused gather+gate+mean+Linear+GELU (proven config: ~104us,
//    FETCH 182MB @ ~2.0TB/s beyond-L2 — the structural wall; 5 configs
//    pinned here). 32 nodes/block, 8 nodes/wave. Per node:
//      Phase A: lane=edge -> {col, |curv diff|} into LDS (once per edge).
//      Phase B: lane (eg,fg) -> float4 x-gather (32-bit saddr) + 4 gates+fmas.
//      Reduce via shfl_xor(16|32); Linear via float4 LDS reads.
// ---------------------------------------------------------------------------
__global__ __launch_bounds__(256) void node_kernel(
    const float* __restrict__ x,    const float* __restrict__ curv,
    const int*   __restrict__ off,  const int* __restrict__ scol,
    const float* __restrict__ Wc,   const float* __restrict__ bc,
    const float* __restrict__ Wl,   const float* __restrict__ bl,
    float* __restrict__ out)
{
    __shared__ float Ws[64][65];
    __shared__ float msl[WPB][64];
    __shared__ int2  ecd[WPB][64];

    const int tid = threadIdx.x;
    #pragma unroll
    for (int i = tid; i < DIM * DIM; i += 256)
        Ws[i >> 6][i & 63] = Wl[i];
    __syncthreads();

    const int sub  = tid >> 6;          // wave in block
    const int lane = tid & 63;
    const int eg   = lane >> 4;         // edge group 0..3
    const int fg   = (lane & 15) << 2;  // feature quad base
    const int d    = lane;              // output feature for Linear

    const float L2E = 1.44269504088896340736f;
    const float4 wc4 = *(const float4*)&Wc[fg];
    const float4 bc4 = *(const float4*)&bc[fg];
    const float wl0 = -wc4.x * L2E, wl1 = -wc4.y * L2E,
                wl2 = -wc4.z * L2E, wl3 = -wc4.w * L2E;
    const float bq0 = -bc4.x * L2E, bq1 = -bc4.y * L2E,
                bq2 = -bc4.z * L2E, bq3 = -bc4.w * L2E;
    const float bld = bl[d];

    const int nbase = blockIdx.x * NPB + sub * NPW;

    for (int i = 0; i < NPW; ++i) {
        const int   node  = nbase + i;
        const int   start = off[node];
        const int   deg   = off[node + 1] - start;
        const float cn    = curv[node];

        float a0 = 0.f, a1 = 0.f, a2 = 0.f, a3 = 0.f;

        for (int kb = 0; kb < deg; kb += 64) {
            const int pn = min(64, deg - kb);
            // Phase A: one lane per edge
            if (lane < pn) {
                int   c  = scol[start + kb + lane];
                float cd = fabsf(cn - curv[c]);
                ecd[sub][lane] = make_int2(c, __float_as_int(cd));
            }
            // Phase B: group eg handles edges k = eg, eg+4, ... < pn
            int k = eg;
            for (; k + 4 < pn; k += 8) {
                int2 p0 = ecd[sub][k];
                int2 p1 = ecd[sub][k + 4];
                float s0 = __int_as_float(p0.y);
                float s1 = __int_as_float(p1.y);
                float4 x0 = *(const float4*)&x[((unsigned)p0.x << 6) + fg];
                float4 x1 = *(const float4*)&x[((unsigned)p1.x << 6) + fg];
                a0 = fmaf(x0.x, fast_gate(s0, wl0, bq0), a0);
                a1 = fmaf(x0.y, fast_gate(s0, wl1, bq1), a1);
                a2 = fmaf(x0.z, fast_gate(s0, wl2, bq2), a2);
                a3 = fmaf(x0.w, fast_gate(s0, wl3, bq3), a3);
                a0 = fmaf(x1.x, fast_gate(s1, wl0, bq0), a0);
                a1 = fmaf(x1.y, fast_gate(s1, wl1, bq1), a1);
                a2 = fmaf(x1.z, fast_gate(s1, wl2, bq2), a2);
                a3 = fmaf(x1.w, fast_gate(s1, wl3, bq3), a3);
            }
            if (k < pn) {
                int2 p0 = ecd[sub][k];
                float s0 = __int_as_float(p0.y);
                float4 x0 = *(const float4*)&x[((unsigned)p0.x << 6) + fg];
                a0 = fmaf(x0.x, fast_gate(s0, wl0, bq0), a0);
                a1 = fmaf(x0.y, fast_gate(s0, wl1, bq1), a1);
                a2 = fmaf(x0.z, fast_gate(s0, wl2, bq2), a2);
                a3 = fmaf(x0.w, fast_gate(s0, wl3, bq3), a3);
            }
        }

        // sum the 4 edge groups
        a0 += __shfl_xor(a0, 16); a0 += __shfl_xor(a0, 32);
        a1 += __shfl_xor(a1, 16); a1 += __shfl_xor(a1, 32);
        a2 += __shfl_xor(a2, 16); a2 += __shfl_xor(a2, 32);
        a3 += __shfl_xor(a3, 16); a3 += __shfl_xor(a3, 32);

        const float inv = __builtin_amdgcn_rcpf(fmaxf((float)deg, 1.0f));
        if (eg == 0)
            *(float4*)&msl[sub][fg] = make_float4(a0 * inv, a1 * inv, a2 * inv, a3 * inv);

        // Linear + GELU (wave-local; compiler inserts lgkmcnt waits)
        float r = bld;
        #pragma unroll
        for (int q = 0; q < DIM; q += 4) {
            float4 mv = *(const float4*)&msl[sub][q];
            float4 wv = *(const float4*)&Ws[d][q];
            r = fmaf(mv.x, wv.x, r);
            r = fmaf(mv.y, wv.y, r);
            r = fmaf(mv.z, wv.z, r);
            r = fmaf(mv.w, wv.w, r);
        }
        out[(size_t)node * DIM + d] = 0.5f * r * (1.0f + erff(r * 0.70710678118654752f));
    }
}

// ---------------------------------------------------------------------------
extern "C" void kernel_launch(void* const* d_in, const int* in_sizes, int n_in,
                              void* d_out, int out_size, void* d_ws, size_t ws_size,
                              hipStream_t stream) {
    const float* x    = (const float*)d_in[0];
    const float* curv = (const float*)d_in[1];
    const float* Wc   = (const float*)d_in[2];
    const float* bc   = (const float*)d_in[3];
    const float* Wl   = (const float*)d_in[4];
    const float* bl   = (const float*)d_in[5];
    const int*   edge = (const int*)d_in[6];

    float* out = (float*)d_out;

    // Workspace layout (~14 MB)
    int* bcnt  = (int*)d_ws;                         // NBUCK (padded to 512)
    int* off   = bcnt + 512;                         // N + 1
    int* bedge = off + N_NODES + 1;                  // NBUCK*BCAP (7.2 MB)
    int* scol  = bedge + NBUCK * BCAP;               // E (6.4 MB)

    hipMemsetAsync(bcnt, 0, 512 * sizeof(int), stream);

    binA_kernel<<<200, 256, 0, stream>>>(edge, bcnt, bedge);
    binC_kernel<<<NBUCK, 256, 0, stream>>>(bcnt, bedge, off, scol);
    node_kernel<<<NODE_BLOCKS, 256, 0, stream>>>(
        x, curv, off, scol, Wc, bc, Wl, bl, out);
}

// Round 12
// 142.782 us; speedup vs baseline: 2.2016x; 1.0551x over previous
//
#include <hip/hip_runtime.h>
#include <math.h>

#define N_NODES 100000
#define N_EDGES 1600000
#define DIM 64

#define RPB   128                // rows per bucket = one node-block
#define NBUCK 782                // ceil(100000/128)
#define BCAP  2432               // mean 2048 + 8 sigma
#define TILE  8000               // edges per binA block; 200 * 8000 = E exact

// sigmoid(s*w+b) = rcp(1 + exp2(s*(-w*log2e) + (-b*log2e)))
__device__ __forceinline__ float fast_gate(float s, float wl, float bl2) {
    return __builtin_amdgcn_rcpf(1.0f + __builtin_amdgcn_exp2f(fmaf(s, wl, bl2)));
}

// ---------------------------------------------------------------------------
// 1) binA: bucket edges by row>>7 into per-bucket regions of bedge[].
//    Per block: LDS histogram -> one global atomic per (block,bucket)
//    reserves a contiguous run -> packed {lrow:7, col:17} stores land in
//    block-exclusive runs (L2-merged writebacks). 156k global atomics.
// ---------------------------------------------------------------------------
__global__ __launch_bounds__(256) void binA_kernel(
    const int* __restrict__ edge, int* __restrict__ bcnt,
    int* __restrict__ bedge)
{
    __shared__ int hist[NBUCK];
    __shared__ int gbase[NBUCK];
    __shared__ int cur[NBUCK];

    const int t  = threadIdx.x;
    const int e0 = blockIdx.x * TILE;

    for (int i = t; i < NBUCK; i += 256) { hist[i] = 0; cur[i] = 0; }
    __syncthreads();

    // pass 1: bucket histogram (rows only)
    for (int i = t; i < TILE; i += 256)
        atomicAdd(&hist[edge[e0 + i] >> 7], 1);
    __syncthreads();

    // reserve one run per non-empty bucket
    for (int i = t; i < NBUCK; i += 256) {
        int h = hist[i];
        gbase[i] = (h > 0) ? (i * BCAP + atomicAdd(&bcnt[i], h)) : 0;
    }
    __syncthreads();

    // pass 2: place packed edges into reserved runs
    for (int i = t; i < TILE; i += 256) {
        int r = edge[e0 + i];
        int c = edge[N_EDGES + e0 + i];
        int b = r >> 7;
        int lrank = atomicAdd(&cur[b], 1);
        int dst = gbase[b] + lrank;
        if (dst < (b + 1) * BCAP)                 // 8-sigma guard, unreachable
            bedge[dst] = ((r & 127) << 17) | c;
    }
}

// ---------------------------------------------------------------------------
// 2) Fused binC + node kernel. Block = bucket (128 rows, 4 waves x 32 nodes).
//    Stage 1 (all 256 threads): read the bucket's packed edges once
//    (coalesced), LDS row-histogram + scan + in-LDS counting sort ->
//    sedge[] sorted by local row. No scol/off global round-trip.
//    Stage 2 (proven gather config, ~2TB/s beyond-L2 wall): per node,
//    Phase A lane=edge -> {col,|curv diff|} into ecd; Phase B float4
//    x-gather + 4 gates+fmas; shfl_xor(16|32) reduce; LDS float4 Linear;
//    exact GELU; coalesced out write.
// ---------------------------------------------------------------------------
__global__ __launch_bounds__(256) void node_kernel(
    const float* __restrict__ x,    const float* __restrict__ curv,
    const int*   __restrict__ bcnt, const int* __restrict__ bedge,
    const float* __restrict__ Wc,   const float* __restrict__ bc,
    const float* __restrict__ Wl,   const float* __restrict__ bl,
    float* __restrict__ out)
{
    __shared__ float Ws[64][65];
    __shared__ float msl[4][64];
    __shared__ int2  ecd[4][64];
    __shared__ int   sedge[BCAP];
    __shared__ int   lhist[RPB];
    __shared__ int   lscan[RPB];
    __shared__ int   loff[RPB];
    __shared__ int   lcur[RPB];

    const int t = threadIdx.x;
    const int b = blockIdx.x;

    #pragma unroll
    for (int i = t; i < DIM * DIM; i += 256)
        Ws[i >> 6][i & 63] = Wl[i];
    if (t < RPB) { lhist[t] = 0; lcur[t] = 0; }
    __syncthreads();

    const int nb  = min(bcnt[b], BCAP);
    const int src = b * BCAP;

    // ---- Stage 1: in-LDS counting sort of the bucket's edges ----
    for (int j = t; j < nb; j += 256)
        atomicAdd(&lhist[bedge[src + j] >> 17], 1);
    __syncthreads();

    if (t < RPB) lscan[t] = lhist[t];
    __syncthreads();
    for (int o = 1; o < RPB; o <<= 1) {
        int u = 0;
        if (t < RPB && t >= o) u = lscan[t - o];
        __syncthreads();
        if (t < RPB) lscan[t] += u;
        __syncthreads();
    }
    if (t < RPB) loff[t] = lscan[t] - lhist[t];
    __syncthreads();

    for (int j = t; j < nb; j += 256) {
        int pv = bedge[src + j];
        int lr = pv >> 17;
        int rk = atomicAdd(&lcur[lr], 1);
        sedge[loff[lr] + rk] = pv & 0x1FFFF;
    }
    __syncthreads();

    // ---- Stage 2: gather + gate + mean + Linear + GELU ----
    const int sub  = t >> 6;            // wave in block
    const int lane = t & 63;
    const int eg   = lane >> 4;         // edge group 0..3
    const int fg   = (lane & 15) << 2;  // feature quad base
    const int d    = lane;              // output feature for Linear

    const float L2E = 1.44269504088896340736f;
    const float4 wc4 = *(const float4*)&Wc[fg];
    const float4 bc4 = *(const float4*)&bc[fg];
    const float wl0 = -wc4.x * L2E, wl1 = -wc4.y * L2E,
                wl2 = -wc4.z * L2E, wl3 = -wc4.w * L2E;
    const float bq0 = -bc4.x * L2E, bq1 = -bc4.y * L2E,
                bq2 = -bc4.z * L2E, bq3 = -bc4.w * L2E;
    const float bld = bl[d];

    for (int i = 0; i < 32; ++i) {
        const int lr   = sub * 32 + i;
        const int node = b * RPB + lr;
        if (node >= N_NODES) break;       // bucket 781 tail (wave-uniform)

        const int   start = loff[lr];
        const int   deg   = lhist[lr];
        const float cn    = curv[node];

        float a0 = 0.f, a1 = 0.f, a2 = 0.f, a3 = 0.f;

        for (int kb = 0; kb < deg; kb += 64) {
            const int pn = min(64, deg - kb);
            // Phase A: one lane per edge (cols now from LDS)
            if (lane < pn) {
                int   c  = sedge[start + kb + lane];
                float cd = fabsf(cn - curv[c]);
                ecd[sub][lane] = make_int2(c, __float_as_int(cd));
            }
            // Phase B: group eg handles edges k = eg, eg+4, ... < pn
            int k = eg;
            for (; k + 4 < pn; k += 8) {
                int2 p0 = ecd[sub][k];
                int2 p1 = ecd[sub][k + 4];
                float s0 = __int_as_float(p0.y);
                float s1 = __int_as_float(p1.y);
                float4 x0 = *(const float4*)&x[((unsigned)p0.x << 6) + fg];
                float4 x1 = *(const float4*)&x[((unsigned)p1.x << 6) + fg];
                a0 = fmaf(x0.x, fast_gate(s0, wl0, bq0), a0);
                a1 = fmaf(x0.y, fast_gate(s0, wl1, bq1), a1);
                a2 = fmaf(x0.z, fast_gate(s0, wl2, bq2), a2);
                a3 = fmaf(x0.w, fast_gate(s0, wl3, bq3), a3);
                a0 = fmaf(x1.x, fast_gate(s1, wl0, bq0), a0);
                a1 = fmaf(x1.y, fast_gate(s1, wl1, bq1), a1);
                a2 = fmaf(x1.z, fast_gate(s1, wl2, bq2), a2);
                a3 = fmaf(x1.w, fast_gate(s1, wl3, bq3), a3);
            }
            if (k < pn) {
                int2 p0 = ecd[sub][k];
                float s0 = __int_as_float(p0.y);
                float4 x0 = *(const float4*)&x[((unsigned)p0.x << 6) + fg];
                a0 = fmaf(x0.x, fast_gate(s0, wl0, bq0), a0);
                a1 = fmaf(x0.y, fast_gate(s0, wl1, bq1), a1);
                a2 = fmaf(x0.z, fast_gate(s0, wl2, bq2), a2);
                a3 = fmaf(x0.w, fast_gate(s0, wl3, bq3), a3);
            }
        }

        // sum the 4 edge groups
        a0 += __shfl_xor(a0, 16); a0 += __shfl_xor(a0, 32);
        a1 += __shfl_xor(a1, 16); a1 += __shfl_xor(a1, 32);
        a2 += __shfl_xor(a2, 16); a2 += __shfl_xor(a2, 32);
        a3 += __shfl_xor(a3, 16); a3 += __shfl_xor(a3, 32);

        const float inv = __builtin_amdgcn_rcpf(fmaxf((float)deg, 1.0f));
        if (eg == 0)
            *(float4*)&msl[sub][fg] = make_float4(a0 * inv, a1 * inv, a2 * inv, a3 * inv);

        // Linear + GELU (wave-local; compiler inserts lgkmcnt waits)
        float r = bld;
        #pragma unroll
        for (int q = 0; q < DIM; q += 4) {
            float4 mv = *(const float4*)&msl[sub][q];
            float4 wv = *(const float4*)&Ws[d][q];
            r = fmaf(mv.x, wv.x, r);
            r = fmaf(mv.y, wv.y, r);
            r = fmaf(mv.z, wv.z, r);
            r = fmaf(mv.w, wv.w, r);
        }
        out[(size_t)node * DIM + d] = 0.5f * r * (1.0f + erff(r * 0.70710678118654752f));
    }
}

// ---------------------------------------------------------------------------
extern "C" void kernel_launch(void* const* d_in, const int* in_sizes, int n_in,
                              void* d_out, int out_size, void* d_ws, size_t ws_size,
                              hipStream_t stream) {
    const float* x    = (const float*)d_in[0];
    const float* curv = (const float*)d_in[1];
    const float* Wc   = (const float*)d_in[2];
    const float* bc   = (const float*)d_in[3];
    const float* Wl   = (const float*)d_in[4];
    const float* bl   = (const float*)d_in[5];
    const int*   edge = (const int*)d_in[6];

    float* out = (float*)d_out;

    // Workspace layout (~7.6 MB)
    int* bcnt  = (int*)d_ws;                         // NBUCK (padded to 1024)
    int* bedge = bcnt + 1024;                        // NBUCK*BCAP (7.6 MB)

    hipMemsetAsync(bcnt, 0, 1024 * sizeof(int), stream);

    binA_kernel<<<200, 256, 0, stream>>>(edge, bcnt, bedge);
    node_kernel<<<NBUCK, 256, 0, stream>>>(
        x, curv, bcnt, bedge, Wc, bc, Wl, bl, out);
}